// Round 1
// baseline (184.079 us; speedup 1.0000x reference)
//
#include <hip/hip_runtime.h>
#include <hip/hip_bf16.h>
#include <math.h>

typedef __bf16 bf16_t;
typedef __bf16 bf16x8 __attribute__((ext_vector_type(8)));
typedef __bf16 bf16x4 __attribute__((ext_vector_type(4)));
typedef float floatx4 __attribute__((ext_vector_type(4)));

#define N_ROWS 4096
#define DIM 512
#define LAM 0.5f

#define GLOBAL_AS(p) ((const __attribute__((address_space(1))) void*)(p))
#define LDS_AS(p) ((__attribute__((address_space(3))) void*)(p))

__global__ void zero_kernel(float* out) {
    if (threadIdx.x == 0) out[0] = 0.0f;
}

// One wave per row: L2-normalize a 512-elem fp32 row, emit bf16.
__global__ __launch_bounds__(256) void normalize_kernel(
    const float* __restrict__ ei, const float* __restrict__ ej,
    bf16_t* __restrict__ Z) {
    const int row  = blockIdx.x * 4 + (threadIdx.x >> 6);   // [0, 8192)
    const int lane = threadIdx.x & 63;
    const float* __restrict__ src = (row < N_ROWS)
        ? (ei + (size_t)row * DIM)
        : (ej + (size_t)(row - N_ROWS) * DIM);
    const float4* src4 = (const float4*)src;
    float4 v0 = src4[lane];
    float4 v1 = src4[lane + 64];
    float s = v0.x*v0.x + v0.y*v0.y + v0.z*v0.z + v0.w*v0.w
            + v1.x*v1.x + v1.y*v1.y + v1.z*v1.z + v1.w*v1.w;
    #pragma unroll
    for (int off = 32; off; off >>= 1) s += __shfl_xor(s, off);
    const float r = rsqrtf(s);
    bf16x4 o0 = { (bf16_t)(v0.x*r), (bf16_t)(v0.y*r), (bf16_t)(v0.z*r), (bf16_t)(v0.w*r) };
    bf16x4 o1 = { (bf16_t)(v1.x*r), (bf16_t)(v1.y*r), (bf16_t)(v1.z*r), (bf16_t)(v1.w*r) };
    bf16x4* dst = (bf16x4*)(Z + (size_t)row * DIM);
    dst[lane]      = o0;
    dst[lane + 64] = o1;
}

// One wave per pair k: pos_k = Z[k] . Z[k+N]; add log1p(exp(-pos+lam))/N.
__global__ __launch_bounds__(256) void positives_kernel(
    const bf16_t* __restrict__ Z, float* __restrict__ out) {
    const int k    = blockIdx.x * 4 + (threadIdx.x >> 6);   // [0, 4096)
    const int lane = threadIdx.x & 63;
    const bf16x8* zi = (const bf16x8*)(Z + (size_t)k * DIM);
    const bf16x8* zj = (const bf16x8*)(Z + (size_t)(k + N_ROWS) * DIM);
    bf16x8 a = zi[lane];
    bf16x8 b = zj[lane];
    float s = 0.0f;
    #pragma unroll
    for (int d = 0; d < 8; ++d) s += (float)a[d] * (float)b[d];
    #pragma unroll
    for (int off = 32; off; off >>= 1) s += __shfl_xor(s, off);
    if (lane == 0) {
        const float f = log1pf(expf(-s + LAM));
        atomicAdd(out, f * (1.0f / (float)N_ROWS));
    }
}

// Fused S = Z.Z^T tile + softplus(S - lam) off-diagonal sum.
// 128x128 tile per block (256 thr = 4 waves in 2x2), BK=32, 16x16x32 bf16 MFMA.
// Upper-triangle blocks only; off-diagonal blocks weighted x2 (S symmetric).
__global__ __launch_bounds__(256) void gemm_fused_kernel(
    const bf16_t* __restrict__ Z, float* __restrict__ out) {
    const int bm = blockIdx.x, bn = blockIdx.y;
    if (bn < bm) return;                      // symmetry: skip lower triangle
    const int t    = threadIdx.x;
    const int w    = t >> 6, lane = t & 63;
    const int wm   = w & 1, wn = w >> 1;      // 2x2 wave grid, 64x64 per wave
    const int q    = lane >> 4, m16 = lane & 15;

    __shared__ bf16_t As[128 * 32];           // 8 KB, row-major, NO padding
    __shared__ bf16_t Bs[128 * 32];           // (global_load_lds layout constraint)
    __shared__ float  red[4];

    floatx4 acc[4][4] = {};

    // staging map: group g covers 8 bf16; 4 groups per 32-elem row
    const int    rA = t >> 2;                 // rows 0..63 (call 1), +64 (call 2)
    const int    cA = (t & 3) * 8;
    const size_t baseA = (size_t)(bm * 128) * DIM;
    const size_t baseB = (size_t)(bn * 128) * DIM;

    for (int kt = 0; kt < DIM; kt += 32) {
        const bf16_t* ga0 = Z + baseA + (size_t)rA * DIM + kt + cA;
        const bf16_t* gb0 = Z + baseB + (size_t)rA * DIM + kt + cA;
        const bf16_t* ga1 = ga0 + 64 * DIM;
        const bf16_t* gb1 = gb0 + 64 * DIM;
        // LDS dest = wave-uniform base + lane*16B
        __builtin_amdgcn_global_load_lds(GLOBAL_AS(ga0), LDS_AS(As + w * 512),        16, 0, 0);
        __builtin_amdgcn_global_load_lds(GLOBAL_AS(ga1), LDS_AS(As + 2048 + w * 512), 16, 0, 0);
        __builtin_amdgcn_global_load_lds(GLOBAL_AS(gb0), LDS_AS(Bs + w * 512),        16, 0, 0);
        __builtin_amdgcn_global_load_lds(GLOBAL_AS(gb1), LDS_AS(Bs + 2048 + w * 512), 16, 0, 0);
        __syncthreads();

        bf16x8 af[4], bfr[4];
        #pragma unroll
        for (int i = 0; i < 4; ++i)
            af[i] = *(const bf16x8*)(As + (wm * 64 + i * 16 + m16) * 32 + q * 8);
        #pragma unroll
        for (int j = 0; j < 4; ++j)
            bfr[j] = *(const bf16x8*)(Bs + (wn * 64 + j * 16 + m16) * 32 + q * 8);
        #pragma unroll
        for (int i = 0; i < 4; ++i)
            #pragma unroll
            for (int j = 0; j < 4; ++j)
                acc[i][j] = __builtin_amdgcn_mfma_f32_16x16x32_bf16(af[i], bfr[j], acc[i][j], 0, 0, 0);
        __syncthreads();
    }

    // Epilogue: C/D map col = lane&15, row = (lane>>4)*4 + reg.
    // One __logf per 16-entry product (max 2.65^16 ~ 6e6, fp32-safe).
    const int rowBase = bm * 128 + wm * 64 + q * 4;
    const int colBase = bn * 128 + wn * 64 + m16;
    float lsum = 0.0f;
    #pragma unroll
    for (int j = 0; j < 4; ++j) {
        const int cg = colBase + j * 16;
        float p = 1.0f;
        #pragma unroll
        for (int i = 0; i < 4; ++i) {
            const int rg0 = rowBase + i * 16;
            #pragma unroll
            for (int r = 0; r < 4; ++r) {
                float e = __expf(acc[i][j][r] - LAM);
                if (rg0 + r == cg) e = 0.0f;   // mask main diagonal
                p *= (1.0f + e);
            }
        }
        lsum += __logf(p);
    }
    if (bm != bn) lsum *= 2.0f;               // symmetric pair (bn, bm)

    #pragma unroll
    for (int off = 32; off; off >>= 1) lsum += __shfl_xor(lsum, off);
    if (lane == 0) red[w] = lsum;
    __syncthreads();
    if (t == 0)
        atomicAdd(out, (red[0] + red[1] + red[2] + red[3]) * (1.0f / (12.0f * (float)N_ROWS)));
}

extern "C" void kernel_launch(void* const* d_in, const int* in_sizes, int n_in,
                              void* d_out, int out_size, void* d_ws, size_t ws_size,
                              hipStream_t stream) {
    const float* ei = (const float*)d_in[0];
    const float* ej = (const float*)d_in[1];
    float* out = (float*)d_out;
    bf16_t* Z = (bf16_t*)d_ws;                // 8192*512*2 B = 8 MB scratch

    zero_kernel<<<1, 64, 0, stream>>>(out);
    normalize_kernel<<<2048, 256, 0, stream>>>(ei, ej, Z);
    positives_kernel<<<1024, 256, 0, stream>>>(Z, out);
    gemm_fused_kernel<<<dim3(64, 64), 256, 0, stream>>>(Z, out);
}